// Round 1
// 67.776 us; speedup vs baseline: 1.0319x; 1.0319x over previous
//
#include <hip/hip_runtime.h>

// Block-per-ray, sort-free composite, payload-deferred.
// Phase 1: AABB slab test + compaction ONLY (4 voxels/thread, float4 loads).
//   Hit body is ~8 instrs: pack 64-bit sort key (ordered-uint tn | voxel id),
//   shared atomicAdd slot, store {key, tn, tf}. All expensive payload math is
//   deferred so the ~60 non-hit lanes of a wave no longer ride through
//   __expf / 27 color loads / sigmoid under divergence.
// Phase 2 (wave 0, dense lanes): lane l owns hit l.
//   Pass A: sigma/alpha/ws/dep (8-sample loop) -> ws into LDS (same-wave
//           RAW, lgkmcnt-ordered).
//   Pass B: T_before for hit l = prod over {j : key_j < key_l} of (1-ws_j)
//           (predicate product over broadcast LDS reads, no sort/scan),
//           proc mask, SH color + sigmoid only for processed hits,
//           butterfly reduce 5 sums, write.
// 2 barriers, ~2.6 KB LDS.

#define BLOCK 256
#define CAP   128
#define EARLY_STOP 0.01f

__global__ __launch_bounds__(BLOCK) void voxel_raster(
    const float* __restrict__ positions, const float* __restrict__ sizes,
    const float* __restrict__ densities, const float* __restrict__ colors,
    const float* __restrict__ ray_o, const float* __restrict__ ray_d,
    float* __restrict__ out, int B)
{
    const int b   = blockIdx.x;
    const int tid = threadIdx.x;

    __shared__ int cnt;
    __shared__ unsigned long long key[CAP];
    __shared__ float h_tn[CAP], h_tf[CAP], h_ws[CAP];

    if (tid == 0) cnt = 0;
    __syncthreads();

    const float ox = ray_o[b*3+0], oy = ray_o[b*3+1], oz = ray_o[b*3+2];
    const float dx = ray_d[b*3+0], dy = ray_d[b*3+1], dz = ray_d[b*3+2];
    const float ivx = 1.0f/dx, ivy = 1.0f/dy, ivz = 1.0f/dz;

    // ---- phase 1: 4 consecutive voxels per thread, AABB + compaction only ----
    const float4 P0 = ((const float4*)positions)[tid*3+0];
    const float4 P1 = ((const float4*)positions)[tid*3+1];
    const float4 P2 = ((const float4*)positions)[tid*3+2];
    const float4 SZ = ((const float4*)sizes)[tid];

    const float pxa[4] = {P0.x, P0.w, P1.z, P2.y};
    const float pya[4] = {P0.y, P1.x, P1.w, P2.z};
    const float pza[4] = {P0.z, P1.y, P2.x, P2.w};
    const float hsa[4] = {SZ.x*0.5f, SZ.y*0.5f, SZ.z*0.5f, SZ.w*0.5f};

    #pragma unroll
    for (int k = 0; k < 4; ++k) {
        const int n = tid*4 + k;
        const float half = hsa[k];
        const float px = pxa[k], py = pya[k], pz = pza[k];

        float a0 = (px - half - ox) * ivx, a1 = (px + half - ox) * ivx;
        float tn = fminf(a0, a1), tf = fmaxf(a0, a1);
        a0 = (py - half - oy) * ivy; a1 = (py + half - oy) * ivy;
        tn = fmaxf(tn, fminf(a0, a1)); tf = fminf(tf, fmaxf(a0, a1));
        a0 = (pz - half - oz) * ivz; a1 = (pz + half - oz) * ivz;
        tn = fmaxf(tn, fminf(a0, a1)); tf = fminf(tf, fmaxf(a0, a1));

        if ((tf > tn) && (tf > 0.0f)) {
            const int slot = atomicAdd(&cnt, 1);
            if (slot < CAP) {
                unsigned u = __float_as_uint(tn);
                u = (u & 0x80000000u) ? ~u : (u | 0x80000000u);
                key[slot]  = ((unsigned long long)u << 32) | (unsigned)n;
                h_tn[slot] = tn;
                h_tf[slot] = tf;
            }
        }
    }
    __syncthreads();

    const int total = cnt;
    const int m = (total < CAP) ? total : CAP;

    // ---- phase 2 (wave 0): dense-lane payload + predicate-product composite ----
    if (tid < 64) {
        // degree-2 real SH basis at ray direction (wave-uniform, only needed here)
        float sh[9];
        sh[0]=1.0f; sh[1]=dy; sh[2]=dz; sh[3]=dx;
        sh[4]=dx*dy; sh[5]=dy*dz; sh[6]=3.0f*dz*dz-1.0f; sh[7]=dx*dz; sh[8]=dx*dx-dy*dy;

        // pass A: per-hit weights (lane l owns hit l; at most 2 hits/lane)
        int   nn[2];
        float ws_l[2], dep_l[2];
        #pragma unroll
        for (int o = 0; o < 2; ++o) {
            const int l = tid + o*64;
            if (l < m) {
                const int n   = (int)(unsigned)key[l];   // low 32 bits = voxel id
                const float tn = h_tn[l], tf = h_tf[l];
                const float sigma = __expf(densities[n]);
                const float dt    = tf - tn;
                const float alpha = 1.0f - __expf(-sigma * dt * 0.125f);
                const float base  = 1.0f - alpha + 1e-8f;
                float pw = 1.0f, ws = 0.0f, dep = 0.0f;
                #pragma unroll
                for (int i = 0; i < 8; i++) {
                    const float w  = alpha * pw;
                    const float ts = tn + dt * ((float)i * (1.0f / 7.0f));
                    ws  += w;
                    dep += w * ts;
                    pw  *= base;
                }
                h_ws[l]  = ws;          // same-wave readers below; lgkmcnt orders
                nn[o]    = n;
                ws_l[o]  = ws;
                dep_l[o] = dep;
            }
        }

        // pass B: predicate product + masked accumulate (color only if processed)
        float ra = 0.f, ga = 0.f, ba = 0.f, da = 0.f, wa = 0.f;
        #pragma unroll
        for (int o = 0; o < 2; ++o) {
            const int l = tid + o*64;
            if (l < m) {
                const unsigned long long kl = key[l];
                float Tb = 1.0f;
                for (int j = 0; j < m; ++j) {          // broadcast LDS reads
                    const unsigned long long kj = key[j];
                    const float wj = h_ws[j];
                    Tb *= (kj < kl) ? (1.0f - wj) : 1.0f;
                }
                if (Tb >= EARLY_STOP) {                // proc mask
                    const int n  = nn[o];
                    const float c = Tb * ws_l[o];
                    float rgb[3];
                    #pragma unroll
                    for (int c3 = 0; c3 < 3; c3++) {
                        float acc = 0.0f;
                        #pragma unroll
                        for (int cc = 0; cc < 9; cc++)
                            acc += sh[cc] * colors[n*27 + c3*9 + cc];
                        rgb[c3] = __fdividef(1.0f, 1.0f + __expf(-acc));
                    }
                    ra += c * rgb[0];
                    ga += c * rgb[1];
                    ba += c * rgb[2];
                    da += Tb * dep_l[o];
                    wa += c;
                }
            }
        }

        // butterfly reduce the 5 sums across the wave
        #pragma unroll
        for (int off = 32; off > 0; off >>= 1) {
            ra += __shfl_down(ra, off, 64);
            ga += __shfl_down(ga, off, 64);
            ba += __shfl_down(ba, off, 64);
            da += __shfl_down(da, off, 64);
            wa += __shfl_down(wa, off, 64);
        }
        if (tid == 0) {
            out[b*3+0] = ra;
            out[b*3+1] = ga;
            out[b*3+2] = ba;
            out[B*3+b] = (total > 0) ? da : 100.0f;   // FAR_PLANE if no hit
            out[B*4+b] = wa;
        }
    }
}

extern "C" void kernel_launch(void* const* d_in, const int* in_sizes, int n_in,
                              void* d_out, int out_size, void* d_ws, size_t ws_size,
                              hipStream_t stream) {
    const float* positions = (const float*)d_in[0];
    const float* sizes     = (const float*)d_in[1];
    const float* densities = (const float*)d_in[2];
    const float* colors    = (const float*)d_in[3];
    const float* ray_o     = (const float*)d_in[4];
    const float* ray_d     = (const float*)d_in[5];
    const int B = in_sizes[4] / 3;      // 2048 rays (N fixed at 1024)

    voxel_raster<<<B, BLOCK, 0, stream>>>(
        positions, sizes, densities, colors, ray_o, ray_d, (float*)d_out, B);
}